// Round 11
// baseline (75.384 us; speedup 1.0000x reference)
//
#include <hip/hip_runtime.h>

// LIF SNN, 50 timesteps x 8192 neurons.
// 1) prep:         x f32 -> bf16 (padded to 64 t, vectorized), zero flag
// 2) ff_gemm_mfma: P[ks][t][j] = sum_{k in chunk} x[t][k]*w_in[j][k] via bf16
//                  MFMA. W staged by global_load_lds DMA (16B) into a
//                  double-buffered, XOR-swizzled LDS tile (r10-proven);
//                  A fragments loaded direct-to-register from L2-hot xb,
//                  pre-issued one step ahead (r5-proven addressing) -> A no
//                  longer occupies the per-step DMA drain window.
// 3) reduce_ff:    FF = sum of 8 bf16 partial planes (vectorized us8)
// 4) spec_scan:    per-neuron scan assuming no spikes (threshold margin ~15
//                  units); 50 FF values prefetched; flags if any spike
// 5) lif_fallback: exact sequential event-driven scan, runs only if flagged.

#define NEUR 8192
#define TSTEPS 50
#define TPAD 64

typedef __attribute__((ext_vector_type(8))) short bs8;           // 8 bf16
typedef __attribute__((ext_vector_type(4))) float fx4;           // MFMA C/D
typedef __attribute__((ext_vector_type(8))) unsigned short us8;  // 8 bf16 bits

static __device__ __forceinline__ unsigned short f2b(float f) {
    // f32 -> bf16 round-to-nearest-even
    unsigned u = __float_as_uint(f);
    return (unsigned short)((u + 0x7FFFu + ((u >> 16) & 1u)) >> 16);
}
static __device__ __forceinline__ float b2f(unsigned short b) {
    return __uint_as_float(((unsigned)b) << 16);
}

// ---------------- K0: convert x (vectorized), zero flag ----------------
__global__ __launch_bounds__(256)
void prep(const float* __restrict__ x, unsigned short* __restrict__ xb,
          int* __restrict__ flag)
{
    const int e8 = blockIdx.x * 256 + threadIdx.x;   // < TPAD*NEUR/8 = 65536
    const int e  = e8 * 8;
    const int t  = e >> 13;
    us8 o;
    if (t < TSTEPS) {
        const float4 lo = *(const float4*)&x[e];
        const float4 hi = *(const float4*)&x[e + 4];
        o = (us8){f2b(lo.x), f2b(lo.y), f2b(lo.z), f2b(lo.w),
                  f2b(hi.x), f2b(hi.y), f2b(hi.z), f2b(hi.w)};
    } else {
        o = (us8){0, 0, 0, 0, 0, 0, 0, 0};
    }
    *(us8*)&xb[e] = o;
    if (e8 == 0) *flag = 0;
}

// ---------------- K1: feed-forward GEMM, W via global_load_lds, A via regs ----------------
// grid = 64 j-blocks (128 j) x 8 k-splits = 512 (2 resident blocks/CU);
// block = 4 waves; 16 steps of BK=64 f32; W tile 32 KB DMA per step.
#define KSPLIT 8
#define KCHUNK (NEUR / KSPLIT)   // 1024
#define BK 64
#define NS (KCHUNK / BK)         // 16

__global__ __launch_bounds__(256)
void ff_gemm_mfma(const float* __restrict__ w,            // [8192][8192]
                  const unsigned short* __restrict__ xb,  // [64][8192] bf16 bits
                  unsigned short* __restrict__ P)         // [KSPLIT][50][8192] bf16
{
    // 64 KB LDS: W double-buffer 2x32 KB (A is register-resident)
    __shared__ __align__(16) unsigned char Wl[2][32768];

    const int tid  = threadIdx.x;
    const int wv   = tid >> 6;
    const int lane = tid & 63;
    const int jb   = blockIdx.x & 63;     // 64 j-blocks
    const int ks   = blockIdx.x >> 6;     // 8 k-splits
    const int j0   = jb * 128;
    const int k0   = ks * KCHUNK;
    const int lrow = lane & 15;           // fragment free-dim index
    const int lgrp = lane >> 4;           // k-group (0..3), 8 k each

    fx4 acc[2][4];
#pragma unroll
    for (int jt = 0; jt < 2; ++jt)
#pragma unroll
        for (int tb = 0; tb < 4; ++tb)
            acc[jt][tb] = (fx4){0.f, 0.f, 0.f, 0.f};

    // A base pointers (bf16 elements, L2/L3-hot; r5-proven addressing)
    const unsigned short* const xq0 = xb + (size_t)lrow * NEUR + k0 + lgrp * 8;
    const unsigned short* const xq1 = xq0 + (size_t)16 * NEUR;
    const unsigned short* const xq2 = xq0 + (size_t)32 * NEUR;
    const unsigned short* const xq3 = xq0 + (size_t)48 * NEUR;

    // two named A register sets: [tb*2 + k2], static indices only
    bs8 AA0[8], AA1[8];

#define A_LOAD(Aset, s)                                          \
    do {                                                         \
        Aset[0] = *(const bs8*)(xq0 + (s) * 64);                 \
        Aset[1] = *(const bs8*)(xq0 + (s) * 64 + 32);            \
        Aset[2] = *(const bs8*)(xq1 + (s) * 64);                 \
        Aset[3] = *(const bs8*)(xq1 + (s) * 64 + 32);            \
        Aset[4] = *(const bs8*)(xq2 + (s) * 64);                 \
        Aset[5] = *(const bs8*)(xq2 + (s) * 64 + 32);            \
        Aset[6] = *(const bs8*)(xq3 + (s) * 64);                 \
        Aset[7] = *(const bs8*)(xq3 + (s) * 64 + 32);            \
    } while (0)

    // --- stage W step s into buffer b: linear LDS dest, inverse-XOR'd source ---
    // W: 128 rows x 256 B (64 f32); LDS 16B-slot c holds global chunk c^(r&7).
#define STAGE_W(s, b)                                                         \
    do {                                                                      \
        _Pragma("unroll") for (int it = 0; it < 8; ++it) {                    \
            const int flat = it * 256 + tid;                                  \
            const int r_ = flat >> 4, c_ = flat & 15;                         \
            const char* g_ = (const char*)w +                                 \
                (((size_t)(j0 + r_) * NEUR + k0 + (s) * BK) * 4)              \
                + ((c_ * 16) ^ ((r_ & 7) << 4));                              \
            __builtin_amdgcn_global_load_lds(g_, &Wl[b][it * 4096 + wv * 1024], \
                                             16, 0, 0);                       \
        }                                                                     \
    } while (0)

    // --- compute one step from W buffer b and A register set ---
#define COMPUTE(b, AS)                                                        \
    do {                                                                      \
        _Pragma("unroll") for (int k2 = 0; k2 < 2; ++k2) {                    \
            bs8 bf0, bf1;                                                     \
            {                                                                 \
                const int rj = wv * 32 + lrow;                                \
                const int sw = (rj & 7) << 4;                                 \
                const int g0 = k2 * 8 + lgrp * 2;                             \
                const float4 lo = *(const float4*)&Wl[b][rj * 256 + ((g0 * 16) ^ sw)];        \
                const float4 hi = *(const float4*)&Wl[b][rj * 256 + (((g0 + 1) * 16) ^ sw)];  \
                bf0 = (bs8){(short)f2b(lo.x), (short)f2b(lo.y), (short)f2b(lo.z),             \
                            (short)f2b(lo.w), (short)f2b(hi.x), (short)f2b(hi.y),             \
                            (short)f2b(hi.z), (short)f2b(hi.w)};              \
            }                                                                 \
            {                                                                 \
                const int rj = wv * 32 + 16 + lrow;                           \
                const int sw = (rj & 7) << 4;                                 \
                const int g0 = k2 * 8 + lgrp * 2;                             \
                const float4 lo = *(const float4*)&Wl[b][rj * 256 + ((g0 * 16) ^ sw)];        \
                const float4 hi = *(const float4*)&Wl[b][rj * 256 + (((g0 + 1) * 16) ^ sw)];  \
                bf1 = (bs8){(short)f2b(lo.x), (short)f2b(lo.y), (short)f2b(lo.z),             \
                            (short)f2b(lo.w), (short)f2b(hi.x), (short)f2b(hi.y),             \
                            (short)f2b(hi.z), (short)f2b(hi.w)};              \
            }                                                                 \
            _Pragma("unroll") for (int tb = 0; tb < 4; ++tb) {                \
                const bs8 a_ = AS[tb * 2 + k2];                               \
                acc[0][tb] = __builtin_amdgcn_mfma_f32_16x16x32_bf16(a_, bf0, acc[0][tb], 0, 0, 0); \
                acc[1][tb] = __builtin_amdgcn_mfma_f32_16x16x32_bf16(a_, bf1, acc[1][tb], 0, 0, 0); \
            }                                                                 \
        }                                                                     \
    } while (0)

    A_LOAD(AA0, 0);
    STAGE_W(0, 0);
    __syncthreads();                       // prologue drain: buf0 + AA0 ready

#pragma unroll 1
    for (int s = 0; s < NS; s += 2) {
        if (s + 1 < NS) { A_LOAD(AA1, s + 1); STAGE_W(s + 1, 1); }
        COMPUTE(0, AA0);
        __syncthreads();                   // drain: buf1 + AA1 ready
        if (s + 2 < NS) { A_LOAD(AA0, s + 2); STAGE_W(s + 2, 0); }
        COMPUTE(1, AA1);
        __syncthreads();                   // drain: buf0 + AA0 ready
    }
#undef A_LOAD
#undef STAGE_W
#undef COMPUTE

    // epilogue: C/D layout col = lane&15 (-> j), row = (lane>>4)*4 + reg (-> t)
#pragma unroll
    for (int jt = 0; jt < 2; ++jt) {
        const int j = j0 + wv * 32 + jt * 16 + lrow;
#pragma unroll
        for (int tb = 0; tb < 4; ++tb)
#pragma unroll
            for (int i = 0; i < 4; ++i) {
                const int t = tb * 16 + lgrp * 4 + i;
                if (t < TSTEPS)
                    P[((size_t)ks * TSTEPS + t) * NEUR + j] = f2b(acc[jt][tb][i]);
            }
    }
}

// ---------------- K2: reduce bf16 partials -> FF f32 ----------------
__global__ __launch_bounds__(256)
void reduce_ff(const unsigned short* __restrict__ P, float* __restrict__ FF)
{
    const int i = (blockIdx.x * 256 + threadIdx.x) * 8;   // 200 blocks
    float s[8];
#pragma unroll
    for (int n = 0; n < 8; ++n) s[n] = 0.f;
#pragma unroll
    for (int ks = 0; ks < KSPLIT; ++ks) {
        const us8 p = *(const us8*)&P[(size_t)ks * TSTEPS * NEUR + i];
#pragma unroll
        for (int n = 0; n < 8; ++n) s[n] += b2f(p[n]);
    }
    *(float4*)&FF[i]     = make_float4(s[0], s[1], s[2], s[3]);
    *(float4*)&FF[i + 4] = make_float4(s[4], s[5], s[6], s[7]);
}

// ---------------- K3: speculative parallel scan (assumes z == 0) ----------------
__global__ __launch_bounds__(256)
void spec_scan(const float* __restrict__ FF, float* __restrict__ out,
               int* __restrict__ flag)
{
    const int j = blockIdx.x * 256 + threadIdx.x;   // one neuron per thread
    float ff[TSTEPS];                               // full prefetch, static idx
#pragma unroll
    for (int t = 0; t < TSTEPS; ++t) ff[t] = FF[(size_t)t * NEUR + j];

    float v = -70.f, cur = 0.f;
    bool any = false;
#pragma unroll
    for (int t = 0; t < TSTEPS; ++t) {
        const float vd = v + 5.0e-5f * ((-70.f - v) + cur);
        const float id = cur - 1.0e-4f * cur;
        const bool sp = vd > -55.f;
        any |= sp;
        v = sp ? -70.f : vd;
        cur = id + ff[t];                           // no recurrence (speculation)
        out[(size_t)t * NEUR + j] = sp ? 1.f : 0.f;
    }
    if (any) atomicAdd(flag, 1);
}

// ---------------- K4: exact event-driven fallback (only if spikes occurred) ----------------
__global__ __launch_bounds__(1024)
void lif_fallback(const float* __restrict__ FF, const float* __restrict__ wrec,
                  float* __restrict__ out, const int* __restrict__ flag)
{
    if (*flag == 0) return;   // speculation was self-consistent -> out is exact

    const int tid = threadIdx.x;
    __shared__ unsigned short list[2][NEUR];
    __shared__ int cnt[2];

    float v[8], cur[8];
#pragma unroll
    for (int n = 0; n < 8; ++n) { v[n] = -70.0f; cur[n] = 0.0f; }
    if (tid == 0) { cnt[0] = 0; cnt[1] = 0; }

    for (int t = 0; t < TSTEPS; ++t) {
        const int rb = t & 1, wb = rb ^ 1;
        __syncthreads();
        if (tid == 0) cnt[wb] = 0;
        __syncthreads();

        float rec[8];
#pragma unroll
        for (int n = 0; n < 8; ++n) rec[n] = 0.0f;
        const int c = cnt[rb];
        for (int s = 0; s < c; ++s) {
            const int k = list[rb][s];
#pragma unroll
            for (int n = 0; n < 8; ++n)
                rec[n] += wrec[(size_t)(tid + n * 1024) * NEUR + k];
        }

#pragma unroll
        for (int n = 0; n < 8; ++n) {
            const float ff = FF[(size_t)t * NEUR + tid + n * 1024];
            const float vd = v[n] + 5.0e-5f * ((-70.0f - v[n]) + cur[n]);
            const float id = cur[n] - 1.0e-4f * cur[n];
            const bool  sp = vd > -55.0f;
            v[n]   = sp ? -70.0f : vd;
            cur[n] = id + ff + rec[n];
            out[(size_t)t * NEUR + tid + n * 1024] = sp ? 1.0f : 0.0f;
            if (sp) {
                const int pos = atomicAdd(&cnt[wb], 1);
                list[wb][pos] = (unsigned short)(tid + n * 1024);
            }
        }
    }
}

extern "C" void kernel_launch(void* const* d_in, const int* in_sizes, int n_in,
                              void* d_out, int out_size, void* d_ws, size_t ws_size,
                              hipStream_t stream) {
    const float* x     = (const float*)d_in[0];   // [50][8192]
    const float* w_in  = (const float*)d_in[1];   // [8192][8192]
    const float* w_rec = (const float*)d_in[2];   // [8192][8192]
    float* out = (float*)d_out;

    // ws layout (16B-aligned):
    //   FF  f32  [50][8192]          1,638,400 B  @ 0
    //   xb  bf16 [64][8192]          1,048,576 B  @ 1,638,400
    //   P   bf16 [8][50][8192]       6,553,600 B  @ 2,686,976
    //   flag int                             4 B  @ 9,240,576
    float* FF          = (float*)d_ws;
    unsigned short* xb = (unsigned short*)((char*)d_ws + 1638400);
    unsigned short* P  = (unsigned short*)((char*)d_ws + 2686976);
    int* flag          = (int*)((char*)d_ws + 9240576);

    prep        <<<dim3(TPAD * NEUR / 8 / 256),   dim3(256),  0, stream>>>(x, xb, flag);
    ff_gemm_mfma<<<dim3(64 * KSPLIT),             dim3(256),  0, stream>>>(w_in, xb, P);
    reduce_ff   <<<dim3(TSTEPS * NEUR / 8 / 256), dim3(256),  0, stream>>>(P, FF);
    spec_scan   <<<dim3(NEUR / 256),              dim3(256),  0, stream>>>(FF, out, flag);
    lif_fallback<<<dim3(1),                       dim3(1024), 0, stream>>>(FF, w_rec, out, flag);
}